// Round 1
// baseline (252.791 us; speedup 1.0000x reference)
//
#include <hip/hip_runtime.h>
#include <hip/hip_cooperative_groups.h>

namespace cg = cooperative_groups;

constexpr int B = 8;
constexpr int N = 1024;
constexpr int NBLOCKS = 256;               // 32 blocks per batch
constexpr int NTHREADS = 512;              // 8 waves
constexpr int NWAVES = NTHREADS / 64;
constexpr int SEG = 32;                    // rows/cols owned per block
constexpr int BLOCKS_PER_BATCH = N / SEG;  // 32
constexpr int MAX_ITER = 100;
constexpr float EPS = 0.1f;
constexpr float INV_EPS = 10.0f;
constexpr float THRESH = 0.1f;
// log(1/1024 + 1e-8)
constexpr float LOG_MU = -6.93146156565634f;
constexpr int KPL = N / 64;                // 16 elements per lane

__device__ inline float wave_sum(float v) {
#pragma unroll
  for (int off = 32; off > 0; off >>= 1) v += __shfl_xor(v, off);
  return v;
}

// Deterministic block-wide sum; every thread returns the same value.
__device__ inline float block_sum(float v, float* sh) {
  v = wave_sum(v);
  const int wave = threadIdx.x >> 6;
  const int lane = threadIdx.x & 63;
  if (lane == 0) sh[wave] = v;
  __syncthreads();
  float tot = 0.f;
#pragma unroll
  for (int w = 0; w < NWAVES; ++w) tot += sh[w];
  __syncthreads();  // protect sh before next reuse
  return tot;
}

__global__ void __launch_bounds__(NTHREADS, 1) sinkhorn_kernel(
    const float* __restrict__ xg, const float* __restrict__ yg,
    float* __restrict__ out, float* __restrict__ ws) {
  // LDS: full batch of points in SoA layout + squared norms (32 KB)
  __shared__ float s_xx[N], s_xy[N], s_xz[N], s_x2[N];
  __shared__ float s_yx[N], s_yy[N], s_yz[N], s_y2[N];
  __shared__ float sh_red[NWAVES];

  float* u = ws;                                     // B*N
  float* v = ws + B * N;                             // B*N
  float* err_part = ws + 2 * B * N;                  // MAX_ITER * NBLOCKS
  float* emd_part = err_part + MAX_ITER * NBLOCKS;   // NBLOCKS

  const int bid = blockIdx.x;
  const int tid = threadIdx.x;
  const int b = bid / BLOCKS_PER_BATCH;
  const int seg = bid % BLOCKS_PER_BATCH;
  const int wave = tid >> 6;
  const int lane = tid & 63;

  // Stage this batch's x, y into LDS and precompute squared norms.
  for (int i = tid; i < N; i += NTHREADS) {
    float a0 = xg[(b * N + i) * 3 + 0];
    float a1 = xg[(b * N + i) * 3 + 1];
    float a2 = xg[(b * N + i) * 3 + 2];
    s_xx[i] = a0; s_xy[i] = a1; s_xz[i] = a2;
    s_x2[i] = a0 * a0 + a1 * a1 + a2 * a2;
    float c0 = yg[(b * N + i) * 3 + 0];
    float c1 = yg[(b * N + i) * 3 + 1];
    float c2 = yg[(b * N + i) * 3 + 2];
    s_yx[i] = c0; s_yy[i] = c1; s_yz[i] = c2;
    s_y2[i] = c0 * c0 + c1 * c1 + c2 * c2;
  }
  // Zero-init u, v (ws is poisoned each launch). Each block owns 32 entries.
  if (tid < SEG) {
    u[b * N + seg * SEG + tid] = 0.f;
    v[b * N + seg * SEG + tid] = 0.f;
  }
  __syncthreads();
  cg::grid_group grid = cg::this_grid();
  grid.sync();

  float* ub = u + b * N;
  float* vb = v + b * N;

  for (int it = 0; it < MAX_ITER; ++it) {
    // ---- u-update: u_new_i = EPS*(LOG_MU - lse_j((v_j - C_ij)/EPS)) ----
    float my_err = 0.f;
    for (int r = wave; r < SEG; r += NWAVES) {
      int i = seg * SEG + r;
      float xi0 = s_xx[i], xi1 = s_xy[i], xi2 = s_xz[i], x2i = s_x2[i];
      float vals[KPL];
      float m = -3.4e38f;
#pragma unroll
      for (int k = 0; k < KPL; ++k) {
        int j = lane + 64 * k;
        float d = xi0 * s_yx[j] + xi1 * s_yy[j] + xi2 * s_yz[j];
        float C = fmaxf(x2i + s_y2[j] - 2.f * d, 0.f);
        float val = (vb[j] - C) * INV_EPS;
        vals[k] = val;
        m = fmaxf(m, val);
      }
#pragma unroll
      for (int off = 32; off > 0; off >>= 1) m = fmaxf(m, __shfl_xor(m, off));
      float s = 0.f;
#pragma unroll
      for (int k = 0; k < KPL; ++k) s += __expf(vals[k] - m);
      s = wave_sum(s);
      float u_new = EPS * (LOG_MU - (m + __logf(s)));
      if (lane == 0) {
        float uo = ub[i];
        my_err += fabsf(u_new - uo);
        ub[i] = u_new;
      }
    }
    float blk_err = block_sum(my_err, sh_red);
    if (tid == 0) err_part[it * NBLOCKS + bid] = blk_err;
    grid.sync();

    // ---- v-update: v_new_j = EPS*(LOG_MU - lse_i((u_i - C_ij)/EPS)) ----
    for (int r = wave; r < SEG; r += NWAVES) {
      int j = seg * SEG + r;
      float yj0 = s_yx[j], yj1 = s_yy[j], yj2 = s_yz[j], y2j = s_y2[j];
      float vals[KPL];
      float m = -3.4e38f;
#pragma unroll
      for (int k = 0; k < KPL; ++k) {
        int i = lane + 64 * k;
        float d = s_xx[i] * yj0 + s_xy[i] * yj1 + s_xz[i] * yj2;
        float C = fmaxf(s_x2[i] + y2j - 2.f * d, 0.f);
        float val = (ub[i] - C) * INV_EPS;
        vals[k] = val;
        m = fmaxf(m, val);
      }
#pragma unroll
      for (int off = 32; off > 0; off >>= 1) m = fmaxf(m, __shfl_xor(m, off));
      float s = 0.f;
#pragma unroll
      for (int k = 0; k < KPL; ++k) s += __expf(vals[k] - m);
      s = wave_sum(s);
      if (lane == 0) vb[j] = EPS * (LOG_MU - (m + __logf(s)));
    }
    grid.sync();

    // ---- convergence check (identical in every block -> uniform break) ----
    float ep = (tid < NBLOCKS) ? err_part[it * NBLOCKS + tid] : 0.f;
    float tot = block_sum(ep, sh_red);
    if (tot * (1.f / (B * N)) < THRESH) break;
  }

  // ---- epilogue: emd = sum_ij exp((u_i + v_j - C_ij)/EPS) * C_ij ----
  float my_emd = 0.f;
  for (int r = wave; r < SEG; r += NWAVES) {
    int i = seg * SEG + r;
    float xi0 = s_xx[i], xi1 = s_xy[i], xi2 = s_xz[i], x2i = s_x2[i];
    float ui = ub[i];
    float acc = 0.f;
#pragma unroll
    for (int k = 0; k < KPL; ++k) {
      int j = lane + 64 * k;
      float d = xi0 * s_yx[j] + xi1 * s_yy[j] + xi2 * s_yz[j];
      float C = fmaxf(x2i + s_y2[j] - 2.f * d, 0.f);
      acc += __expf((ui + vb[j] - C) * INV_EPS) * C;
    }
    acc = wave_sum(acc);
    if (lane == 0) my_emd += acc;
  }
  float blk = block_sum(my_emd, sh_red);
  if (tid == 0) emd_part[bid] = blk;
  grid.sync();

  float ep2 = (tid < NBLOCKS) ? emd_part[tid] : 0.f;
  float tot2 = block_sum(ep2, sh_red);
  if (bid == 0 && tid == 0) out[0] = tot2 * (1.f / B);
}

extern "C" void kernel_launch(void* const* d_in, const int* in_sizes, int n_in,
                              void* d_out, int out_size, void* d_ws, size_t ws_size,
                              hipStream_t stream) {
  const float* x = (const float*)d_in[0];
  const float* y = (const float*)d_in[1];
  float* out = (float*)d_out;
  float* ws = (float*)d_ws;
  void* args[] = { (void*)&x, (void*)&y, (void*)&out, (void*)&ws };
  hipLaunchCooperativeKernel((const void*)sinkhorn_kernel,
                             dim3(NBLOCKS), dim3(NTHREADS), args, 0, stream);
}